// Round 4
// baseline (21544.420 us; speedup 1.0000x reference)
//
#include <hip/hip_runtime.h>

#define T_STEPS 1000
#define NI 700
#define NIQ 11          /* ceil(NI/64) input mask qwords */
#define NH 4096
#define NO 20

#define ALPHA 0.8187307530779818f   /* exp(-0.2)  synaptic decay */
#define BETA  0.9048374180359595f   /* exp(-0.1)  membrane decay */

#define NBH 64          /* hidden blocks */
#define NPB 64          /* neurons per hidden block */
#define BLOCK 1024      /* 16 waves */
#define NWAVE 16
#define SPW 4           /* source blocks owned per wave */

typedef unsigned long long u64;
typedef unsigned int u32;

/* ---------------- transpose: out[c*R + r] = in[r*C + c] ---------------- */
__global__ void __launch_bounds__(256)
tpose_kernel(const float* __restrict__ in, float* __restrict__ out, int R, int C)
{
    __shared__ float tile[32][33];
    const int c  = blockIdx.x * 32 + threadIdx.x;
    const int r0 = blockIdx.y * 32;
    for (int dy = threadIdx.y; dy < 32; dy += 8) {
        const int r = r0 + dy;
        if (r < R && c < C) tile[dy][threadIdx.x] = in[(size_t)r * C + c];
    }
    __syncthreads();
    const int r2 = r0 + threadIdx.x;
    for (int dy = threadIdx.y; dy < 32; dy += 8) {
        const int c2 = blockIdx.x * 32 + dy;
        if (c2 < C && r2 < R) out[(size_t)c2 * R + r2] = tile[threadIdx.x][dy];
    }
}

/* -------- precompute input spike bitmasks: msk[t][q] over all T -------- */
__global__ void __launch_bounds__(256)
inpmask_kernel(const float* __restrict__ in, u64* __restrict__ msk)
{
    const int t    = blockIdx.x * 4 + (threadIdx.x >> 6);
    const int lane = threadIdx.x & 63;
    if (t >= T_STEPS) return;
    const float* __restrict__ row = in + (size_t)t * NI;
    for (int q = 0; q < NIQ; ++q) {
        const int j = q * 64 + lane;
        const u64 m = __ballot(j < NI && row[j] > 0.5f);
        if (lane == 0) msk[t * 16 + q] = m;
    }
}

/* ---------------- persistent SNN kernel ---------------- */
/* mb layout: [T][NBH] entries of 4 u32 {mask_lo, mask_hi, tag, pad}; tag==t+1
   after step t's spikes are published. Poison (0xAAAAAAAA) never equals a
   valid tag, so no initialization is required. */
__global__ void __launch_bounds__(BLOCK)
snn_kernel(const u64*  __restrict__ inpMask,  /* [T][16] */
           const float* __restrict__ W_ro,    /* [NO, NH] row-major */
           const float* __restrict__ W_inT,   /* [NI, NH] */
           const float* __restrict__ W_fbT,   /* [NH, NH] */
           float* __restrict__ out,           /* [NO, T] */
           u32*   __restrict__ mb)            /* [T][NBH][4] tagged masks */
{
    const int tid  = threadIdx.x;
    const int lane = tid & 63;
    const int w    = tid >> 6;
    const int b    = blockIdx.x;

    /* ================= readout block (fully off the critical path) ========= */
    if (b == NBH) {
        __shared__ u64 smask[NBH];
        __shared__ int roff[NBH];
        __shared__ int actR[NH];
        __shared__ int actRn;
        float mem2 = 0.f, syn2 = 0.f;

        for (int t = 0; t < T_STEPS; ++t) {
            if (tid < NBH) {        /* wave0: 64 lanes spin on 64 tagged masks */
                const u32* tg = &mb[((size_t)t * NBH + tid) * 4];
                u32 v;
                do {
                    v = __hip_atomic_load(tg + 2, __ATOMIC_ACQUIRE,
                                          __HIP_MEMORY_SCOPE_AGENT);
                } while (v != (u32)(t + 1));
                const u32 lo = __hip_atomic_load(tg + 0, __ATOMIC_RELAXED,
                                                 __HIP_MEMORY_SCOPE_AGENT);
                const u32 hi = __hip_atomic_load(tg + 1, __ATOMIC_RELAXED,
                                                 __HIP_MEMORY_SCOPE_AGENT);
                smask[tid] = ((u64)hi << 32) | lo;
            }
            __syncthreads();

            if (w == 0) {           /* scan counts -> offsets; extract indices */
                const u64 m = smask[lane];
                const int cnt = __popcll(m);
                int v = cnt;
                #pragma unroll
                for (int d = 1; d < 64; d <<= 1) {
                    const int u = __shfl_up(v, d, 64);
                    if (lane >= d) v += u;
                }
                int o = v - cnt;
                if (lane == 63) actRn = v;
                u64 mm = m;
                const int base = lane * 64;
                while (mm) {
                    const int bit = __builtin_ctzll(mm);
                    mm &= mm - 1;
                    actR[o++] = base + bit;
                }
            }
            __syncthreads();

            const int nR = actRn;
            if (tid < NO * 32) {    /* 32 threads per output row */
                const int o = tid >> 5, k = tid & 31;
                float rc = 0.f;
                for (int n = k; n < nR; n += 32) rc += W_ro[o * NH + actR[n]];
                #pragma unroll
                for (int d = 16; d; d >>= 1) rc += __shfl_xor(rc, d, 32);
                if (k == 0) {
                    const float m2n = mem2 * BETA + syn2;
                    out[o * T_STEPS + t] = m2n;
                    syn2 = syn2 * ALPHA + rc;
                    mem2 = m2n;
                }
            }
            __syncthreads();
        }
        return;
    }

    /* ================= hidden block ================= */
    __shared__ float pcur[2][BLOCK];          /* double-buffered partials */
    __shared__ int   wlH[NWAVE][SPW * 64];    /* per-wave hidden index lists */
    __shared__ int   wlI[NWAVE][64];          /* per-wave input index lists */

    const int i   = b * NPB + lane;           /* this block's weight column */
    const int bb0 = w * SPW;                  /* source blocks owned by wave */
    const int qw  = (w >= NWAVE - NIQ) ? (w - (NWAVE - NIQ)) : -1;
    float mem1 = 0.f, syn1 = 0.f, sflag = 0.f;

    for (int t = 0; t < T_STEPS; ++t) {
        /* ---- input part first: overlaps producers' publish latency ---- */
        int cntI = 0;
        if (qw >= 0) {
            const u64 m = inpMask[(size_t)t * 16 + qw];
            if ((m >> lane) & 1)
                wlI[w][__popcll(m & ((1ULL << lane) - 1))] = qw * 64 + lane;
            cntI = __popcll(m);
        }

        /* ---- poll own 4 producers' tagged masks (step t-1) ---- */
        int cntH = 0;
        if (t > 0) {
            u64 mk = 0;
            {
                const bool need = lane < SPW;
                const u32* tg = &mb[((size_t)(t - 1) * NBH + bb0 + (lane & (SPW - 1))) * 4];
                bool rdy = !need;
                while (__ballot(!rdy)) {
                    if (!rdy) {
                        const u32 v = __hip_atomic_load(tg + 2, __ATOMIC_ACQUIRE,
                                                        __HIP_MEMORY_SCOPE_AGENT);
                        rdy = (v == (u32)t);
                    }
                }
                if (need) {
                    const u32 lo = __hip_atomic_load(tg + 0, __ATOMIC_RELAXED,
                                                     __HIP_MEMORY_SCOPE_AGENT);
                    const u32 hi = __hip_atomic_load(tg + 1, __ATOMIC_RELAXED,
                                                     __HIP_MEMORY_SCOPE_AGENT);
                    mk = ((u64)hi << 32) | lo;
                }
            }
            /* bit-parallel extraction: lane L handles bit L of each mask */
            #pragma unroll
            for (int s = 0; s < SPW; ++s) {
                const u64 m = __shfl(mk, s, 64);
                if ((m >> lane) & 1)
                    wlH[w][cntH + __popcll(m & ((1ULL << lane) - 1))] = (bb0 + s) * 64 + lane;
                cntH += __popcll(m);
            }
        }

        /* ---- gather: groups of 8 with 4 independent accumulators ---- */
        float a0 = 0.f, a1 = 0.f, a2 = 0.f, a3 = 0.f;
        {
            const float* __restrict__ Wf = W_fbT + i;
            const int* wl = wlH[w];
            int n = 0;
            for (; n + 8 <= cntH; n += 8) {
                const int4 i0 = *(const int4*)&wl[n];
                const int4 i1 = *(const int4*)&wl[n + 4];
                a0 += Wf[(size_t)i0.x * NH]; a1 += Wf[(size_t)i0.y * NH];
                a2 += Wf[(size_t)i0.z * NH]; a3 += Wf[(size_t)i0.w * NH];
                a0 += Wf[(size_t)i1.x * NH]; a1 += Wf[(size_t)i1.y * NH];
                a2 += Wf[(size_t)i1.z * NH]; a3 += Wf[(size_t)i1.w * NH];
            }
            #pragma unroll
            for (int q = 0; q < 7; ++q) {       /* predicated tail, one RT */
                const int nm = n + q;
                if (nm < cntH) {
                    float v = Wf[(size_t)wl[nm] * NH];
                    if (q & 1) a1 += v; else a0 += v;
                }
            }
            const float* __restrict__ Wi = W_inT + i;
            const int* wli = wlI[w];
            n = 0;
            for (; n + 4 <= cntI; n += 4) {
                const int4 i0 = *(const int4*)&wli[n];
                a0 += Wi[(size_t)i0.x * NH]; a1 += Wi[(size_t)i0.y * NH];
                a2 += Wi[(size_t)i0.z * NH]; a3 += Wi[(size_t)i0.w * NH];
            }
            #pragma unroll
            for (int q = 0; q < 3; ++q) {
                const int nm = n + q;
                if (nm < cntI) {
                    float v = Wi[(size_t)wli[nm] * NH];
                    if (q & 1) a3 += v; else a2 += v;
                }
            }
        }
        const int p = t & 1;
        pcur[p][tid] = (a0 + a1) + (a2 + a3);
        __syncthreads();                       /* the ONLY barrier per step */

        /* ---- LIF update + publish (wave 0 owns the 64 neurons) ---- */
        if (w == 0) {
            float cur = 0.f;
            #pragma unroll
            for (int ww = 0; ww < NWAVE; ++ww) cur += pcur[p][lane + 64 * ww];
            mem1 *= (1.f - sflag);
            const float onew = (mem1 - 1.0f > 0.f) ? 1.f : 0.f;
            mem1 = mem1 * BETA + syn1;
            syn1 = syn1 * ALPHA + cur;
            sflag = onew;
            const u64 sm = __ballot(onew > 0.f);
            if (lane == 0) {
                u32* tg = &mb[((size_t)t * NBH + b) * 4];
                __hip_atomic_store(tg + 0, (u32)sm, __ATOMIC_RELAXED,
                                   __HIP_MEMORY_SCOPE_AGENT);
                __hip_atomic_store(tg + 1, (u32)(sm >> 32), __ATOMIC_RELAXED,
                                   __HIP_MEMORY_SCOPE_AGENT);
                __hip_atomic_store(tg + 2, (u32)(t + 1), __ATOMIC_RELEASE,
                                   __HIP_MEMORY_SCOPE_AGENT);
            }
        }
        /* no second barrier: pcur is double-buffered; waves can't wrap past
           the next barrier until wave 0 arrives there */
    }
}

extern "C" void kernel_launch(void* const* d_in, const int* in_sizes, int n_in,
                              void* d_out, int out_size, void* d_ws, size_t ws_size,
                              hipStream_t stream)
{
    const float* inp  = (const float*)d_in[0];   /* [T, NI]  */
    const float* W_in = (const float*)d_in[1];   /* [NH, NI] */
    const float* W_fb = (const float*)d_in[2];   /* [NH, NH] */
    const float* W_ro = (const float*)d_in[3];   /* [NO, NH] */
    float* out = (float*)d_out;

    char* ws = (char*)d_ws;
    size_t off = 0;
    auto alloc = [&](size_t bytes) -> void* {
        void* p = ws + off;
        off = (off + bytes + 255) & ~(size_t)255;
        return p;
    };
    float* W_fbT   = (float*)alloc(sizeof(float) * (size_t)NH * NH);
    float* W_inT   = (float*)alloc(sizeof(float) * (size_t)NI * NH);
    u64*   inpMask = (u64*)alloc(sizeof(u64) * (size_t)T_STEPS * 16);
    u32*   mb      = (u32*)alloc(sizeof(u32) * (size_t)T_STEPS * NBH * 4);

    dim3 tb(32, 8);
    tpose_kernel<<<dim3((NH + 31) / 32, (NH + 31) / 32), tb, 0, stream>>>(W_fb, W_fbT, NH, NH);
    tpose_kernel<<<dim3((NI + 31) / 32, (NH + 31) / 32), tb, 0, stream>>>(W_in, W_inT, NH, NI);
    inpmask_kernel<<<(T_STEPS + 3) / 4, 256, 0, stream>>>(inp, inpMask);

    snn_kernel<<<NBH + 1, BLOCK, 0, stream>>>(inpMask, W_ro, W_inT, W_fbT, out, mb);
}

// Round 6
// 7735.811 us; speedup vs baseline: 2.7850x; 2.7850x over previous
//
#include <hip/hip_runtime.h>

#define T_STEPS 1000
#define NI 700
#define NIQ 11          /* ceil(NI/64) input mask qwords */
#define NH 4096
#define NO 20

#define ALPHA 0.8187307530779818f   /* exp(-0.2)  synaptic decay */
#define BETA  0.9048374180359595f   /* exp(-0.1)  membrane decay */

#define NBH 64          /* hidden blocks */
#define NPB 64          /* neurons per hidden block */
#define BLOCK 1024      /* 16 waves */
#define NWAVE 16
#define SPW 4           /* source blocks owned per wave */
#define SLOTW 16        /* u32 per mask slot = 64B: one cacheline, one writer */

typedef unsigned long long u64;
typedef unsigned int u32;
typedef int v4i __attribute__((ext_vector_type(4)));

/* single-transaction 16B publish/poll, bypassing L1/L2 (to coherence point),
   with NO buffer_inv (unlike acquire atomics) and NO fences needed: the tag
   and the masks travel in the same 16B packet. */
__device__ __forceinline__ void pub16(u32* p, v4i v)
{
    asm volatile("global_store_dwordx4 %0, %1, off sc0 sc1"
                 :: "v"((u64)(uintptr_t)p), "v"(v) : "memory");
}
__device__ __forceinline__ v4i poll16(const u32* p)
{
    v4i r;
    asm volatile("global_load_dwordx4 %0, %1, off sc0 sc1\n\ts_waitcnt vmcnt(0)"
                 : "=v"(r) : "v"((u64)(uintptr_t)p) : "memory");
    return r;
}

/* ---------------- transpose: out[c*R + r] = in[r*C + c] ---------------- */
__global__ void __launch_bounds__(256)
tpose_kernel(const float* __restrict__ in, float* __restrict__ out, int R, int C)
{
    __shared__ float tile[32][33];
    const int c  = blockIdx.x * 32 + threadIdx.x;
    const int r0 = blockIdx.y * 32;
    for (int dy = threadIdx.y; dy < 32; dy += 8) {
        const int r = r0 + dy;
        if (r < R && c < C) tile[dy][threadIdx.x] = in[(size_t)r * C + c];
    }
    __syncthreads();
    const int r2 = r0 + threadIdx.x;
    for (int dy = threadIdx.y; dy < 32; dy += 8) {
        const int c2 = blockIdx.x * 32 + dy;
        if (c2 < C && r2 < R) out[(size_t)c2 * R + r2] = tile[threadIdx.x][dy];
    }
}

/* -------- precompute input spike bitmasks: msk[t][q] over all T -------- */
__global__ void __launch_bounds__(256)
inpmask_kernel(const float* __restrict__ in, u64* __restrict__ msk)
{
    const int t    = blockIdx.x * 4 + (threadIdx.x >> 6);
    const int lane = threadIdx.x & 63;
    if (t >= T_STEPS) return;
    const float* __restrict__ row = in + (size_t)t * NI;
    for (int q = 0; q < NIQ; ++q) {
        const int j = q * 64 + lane;
        const u64 m = __ballot(j < NI && row[j] > 0.5f);
        if (lane == 0) msk[t * 16 + q] = m;
    }
}

/* ---------------- persistent SNN kernel ----------------
   mb: [T][NBH] slots of SLOTW u32 (64B, single writer). dwords {lo,hi,tag,0};
   tag==t+1 once step t's spikes from block b are published. memset-0 before
   launch so stale tags from a previous graph replay are impossible. */
__global__ void __launch_bounds__(BLOCK)
snn_kernel(const u64*  __restrict__ inpMask,  /* [T][16] */
           const float* __restrict__ W_ro,    /* [NO, NH] row-major */
           const float* __restrict__ W_inT,   /* [NI, NH] */
           const float* __restrict__ W_fbT,   /* [NH, NH] */
           float* __restrict__ out,           /* [NO, T] */
           u32*   __restrict__ mb)
{
    const int tid  = threadIdx.x;
    const int lane = tid & 63;
    const int w    = tid >> 6;
    const int b    = blockIdx.x;

    /* ================= readout block (lags freely; full history) ========= */
    if (b == NBH) {
        __shared__ int actR[NH];
        __shared__ int actRn;
        float mem2 = 0.f, syn2 = 0.f;

        for (int t = 0; t < T_STEPS; ++t) {
            if (w == 0) {           /* 64 lanes poll 64 producer slots */
                const u32* tg = &mb[((size_t)t * NBH + lane) * SLOTW];
                v4i r;
                do { r = poll16(tg); } while ((u32)r.z != (u32)(t + 1));
                const u64 m = ((u64)(u32)r.y << 32) | (u32)r.x;
                const int cnt = __popcll(m);
                int v = cnt;
                #pragma unroll
                for (int d = 1; d < 64; d <<= 1) {
                    const int u = __shfl_up(v, d, 64);
                    if (lane >= d) v += u;
                }
                int o = v - cnt;
                if (lane == 63) actRn = v;
                u64 mm = m;
                const int base = lane * 64;
                while (mm) {
                    const int bit = __builtin_ctzll(mm);
                    mm &= mm - 1;
                    actR[o++] = base + bit;
                }
            }
            __syncthreads();

            const int nR = actRn;
            if (tid < NO * 32) {    /* 32 threads per output; 4-way unrolled */
                const int o = tid >> 5, k = tid & 31;
                const float* __restrict__ Wr = W_ro + o * NH;
                float r0 = 0.f, r1 = 0.f, r2 = 0.f, r3 = 0.f;
                int n = k;
                for (; n + 96 < nR; n += 128) {
                    r0 += Wr[actR[n]];      r1 += Wr[actR[n + 32]];
                    r2 += Wr[actR[n + 64]]; r3 += Wr[actR[n + 96]];
                }
                for (; n < nR; n += 32) r0 += Wr[actR[n]];
                float rc = (r0 + r1) + (r2 + r3);
                #pragma unroll
                for (int d = 16; d; d >>= 1) rc += __shfl_xor(rc, d, 32);
                if (k == 0) {
                    const float m2n = mem2 * BETA + syn2;
                    out[o * T_STEPS + t] = m2n;
                    syn2 = syn2 * ALPHA + rc;
                    mem2 = m2n;
                }
            }
            __syncthreads();        /* actR safe to overwrite next iter */
        }
        return;
    }

    /* ================= hidden block ================= */
    __shared__ float pcur[2][BLOCK];          /* double-buffered partials */
    __shared__ int   wlH[NWAVE][SPW * 64];    /* per-wave hidden index lists */
    __shared__ int   wlI[NWAVE][64];          /* per-wave input index lists */

    const int i   = b * NPB + lane;           /* this block's weight column */
    const int bb0 = w * SPW;                  /* source blocks owned by wave */
    const int qw  = (w >= NWAVE - NIQ) ? (w - (NWAVE - NIQ)) : -1;
    float mem1 = 0.f, syn1 = 0.f, sflag = 0.f;

    for (int t = 0; t < T_STEPS; ++t) {
        float a0 = 0.f, a1 = 0.f, a2 = 0.f, a3 = 0.f;

        /* ---- input extract + gather FIRST: overlaps producers' publish --- */
        int cntI = 0;
        if (qw >= 0) {
            const u64 m = inpMask[(size_t)t * 16 + qw];
            if ((m >> lane) & 1)
                wlI[w][__popcll(m & ((1ULL << lane) - 1))] = qw * 64 + lane;
            cntI = __popcll(m);
        }
        {
            const float* __restrict__ Wi = W_inT + i;
            const int* wli = wlI[w];
            int n = 0;
            for (; n + 4 <= cntI; n += 4) {
                const int4 i0 = *(const int4*)&wli[n];
                a0 += Wi[(size_t)i0.x * NH]; a1 += Wi[(size_t)i0.y * NH];
                a2 += Wi[(size_t)i0.z * NH]; a3 += Wi[(size_t)i0.w * NH];
            }
            #pragma unroll
            for (int q = 0; q < 3; ++q) {
                const int nm = n + q;
                if (nm < cntI) {
                    const float v = Wi[(size_t)wli[nm] * NH];
                    if (q & 1) a3 += v; else a2 += v;
                }
            }
        }

        /* ---- poll own SPW producers' packets (step t-1), 1 RT each ---- */
        int cntH = 0;
        if (t > 0) {
            u64 mk = 0;
            if (lane < SPW) {
                const u32* tg = &mb[((size_t)(t - 1) * NBH + bb0 + lane) * SLOTW];
                v4i r;
                do { r = poll16(tg); } while ((u32)r.z != (u32)t);
                mk = ((u64)(u32)r.y << 32) | (u32)r.x;
            }
            /* bit-parallel extraction: lane L handles bit L of each mask */
            #pragma unroll
            for (int s = 0; s < SPW; ++s) {
                const u64 m = __shfl(mk, s, 64);
                if ((m >> lane) & 1)
                    wlH[w][cntH + __popcll(m & ((1ULL << lane) - 1))] = (bb0 + s) * 64 + lane;
                cntH += __popcll(m);
            }
        }

        /* ---- feedback gather: groups of 8, 4 independent accumulators --- */
        {
            const float* __restrict__ Wf = W_fbT + i;
            const int* wl = wlH[w];
            int n = 0;
            for (; n + 8 <= cntH; n += 8) {
                const int4 i0 = *(const int4*)&wl[n];
                const int4 i1 = *(const int4*)&wl[n + 4];
                a0 += Wf[(size_t)i0.x * NH]; a1 += Wf[(size_t)i0.y * NH];
                a2 += Wf[(size_t)i0.z * NH]; a3 += Wf[(size_t)i0.w * NH];
                a0 += Wf[(size_t)i1.x * NH]; a1 += Wf[(size_t)i1.y * NH];
                a2 += Wf[(size_t)i1.z * NH]; a3 += Wf[(size_t)i1.w * NH];
            }
            #pragma unroll
            for (int q = 0; q < 7; ++q) {
                const int nm = n + q;
                if (nm < cntH) {
                    const float v = Wf[(size_t)wl[nm] * NH];
                    if (q & 1) a1 += v; else a0 += v;
                }
            }
        }
        const int p = t & 1;
        pcur[p][tid] = (a0 + a1) + (a2 + a3);
        __syncthreads();                       /* the ONLY barrier per step */

        /* ---- LIF update + single-packet publish (wave 0 owns neurons) --- */
        if (w == 0) {
            float cur = 0.f;
            #pragma unroll
            for (int ww = 0; ww < NWAVE; ++ww) cur += pcur[p][lane + 64 * ww];
            mem1 *= (1.f - sflag);
            const float onew = (mem1 - 1.0f > 0.f) ? 1.f : 0.f;
            mem1 = mem1 * BETA + syn1;
            syn1 = syn1 * ALPHA + cur;
            sflag = onew;
            const u64 sm = __ballot(onew > 0.f);
            if (lane == 0) {
                v4i pkt;
                pkt.x = (int)(u32)sm;
                pkt.y = (int)(u32)(sm >> 32);
                pkt.z = (int)(u32)(t + 1);
                pkt.w = 0;
                pub16(&mb[((size_t)t * NBH + b) * SLOTW], pkt);
            }
        }
        /* no second barrier: pcur double-buffered; wl/pcur wrap hazards are
           blocked by the next iteration's barrier requiring wave 0 */
    }
}

extern "C" void kernel_launch(void* const* d_in, const int* in_sizes, int n_in,
                              void* d_out, int out_size, void* d_ws, size_t ws_size,
                              hipStream_t stream)
{
    const float* inp  = (const float*)d_in[0];   /* [T, NI]  */
    const float* W_in = (const float*)d_in[1];   /* [NH, NI] */
    const float* W_fb = (const float*)d_in[2];   /* [NH, NH] */
    const float* W_ro = (const float*)d_in[3];   /* [NO, NH] */
    float* out = (float*)d_out;

    char* ws = (char*)d_ws;
    size_t off = 0;
    auto alloc = [&](size_t bytes) -> void* {
        void* p = ws + off;
        off = (off + bytes + 255) & ~(size_t)255;
        return p;
    };
    float* W_fbT   = (float*)alloc(sizeof(float) * (size_t)NH * NH);
    float* W_inT   = (float*)alloc(sizeof(float) * (size_t)NI * NH);
    u64*   inpMask = (u64*)alloc(sizeof(u64) * (size_t)T_STEPS * 16);
    u32*   mb      = (u32*)alloc(sizeof(u32) * (size_t)T_STEPS * NBH * SLOTW);

    /* stale same-valued tags from a previous replay must be impossible */
    (void)hipMemsetAsync(mb, 0, sizeof(u32) * (size_t)T_STEPS * NBH * SLOTW, stream);

    dim3 tb(32, 8);
    tpose_kernel<<<dim3((NH + 31) / 32, (NH + 31) / 32), tb, 0, stream>>>(W_fb, W_fbT, NH, NH);
    tpose_kernel<<<dim3((NI + 31) / 32, (NH + 31) / 32), tb, 0, stream>>>(W_in, W_inT, NH, NI);
    inpmask_kernel<<<(T_STEPS + 3) / 4, 256, 0, stream>>>(inp, inpMask);

    snn_kernel<<<NBH + 1, BLOCK, 0, stream>>>(inpMask, W_ro, W_inT, W_fbT, out, mb);
}

// Round 7
// 3708.019 us; speedup vs baseline: 5.8102x; 2.0862x over previous
//
#include <hip/hip_runtime.h>

#define T_STEPS 1000
#define NI 700
#define NIQ 11          /* ceil(NI/64) input mask qwords */
#define NH 4096
#define NO 20

#define ALPHA 0.8187307530779818f   /* exp(-0.2)  synaptic decay */
#define BETA  0.9048374180359595f   /* exp(-0.1)  membrane decay */

#define NBH 64          /* hidden blocks */
#define BLOCK 1024      /* 16 waves */
#define NWAVE 16
#define SPW 4           /* source blocks owned per wave */
#define SLOTW 16        /* u32 per mask slot = 64B line, single writer */
#define NCH 6           /* prefetch chunks of 8 -> 48 register window */
#define CAP (NCH * 8)
#define WLCAP 328       /* 320 max list + pad */
#define ZROW NI         /* zero row index in unified weight matrix */
#define NROWS (NI + 1 + NH)

typedef unsigned long long u64;
typedef unsigned int u32;
typedef int v4i __attribute__((ext_vector_type(4)));

/* single-transaction 16B publish/poll to the device coherence point:
   tag+mask travel in one packet; no buffer_inv, no fences needed. */
__device__ __forceinline__ void pub16(u32* p, v4i v)
{
    asm volatile("global_store_dwordx4 %0, %1, off sc0 sc1"
                 :: "v"((u64)(uintptr_t)p), "v"(v) : "memory");
}
__device__ __forceinline__ v4i poll16(const u32* p)
{
    v4i r;
    asm volatile("global_load_dwordx4 %0, %1, off sc0 sc1\n\ts_waitcnt vmcnt(0)"
                 : "=v"(r) : "v"((u64)(uintptr_t)p) : "memory");
    return r;
}

/* ---------------- transpose: out[c*R + r] = in[r*C + c] ---------------- */
__global__ void __launch_bounds__(256)
tpose_kernel(const float* __restrict__ in, float* __restrict__ out, int R, int C)
{
    __shared__ float tile[32][33];
    const int c  = blockIdx.x * 32 + threadIdx.x;
    const int r0 = blockIdx.y * 32;
    for (int dy = threadIdx.y; dy < 32; dy += 8) {
        const int r = r0 + dy;
        if (r < R && c < C) tile[dy][threadIdx.x] = in[(size_t)r * C + c];
    }
    __syncthreads();
    const int r2 = r0 + threadIdx.x;
    for (int dy = threadIdx.y; dy < 32; dy += 8) {
        const int c2 = blockIdx.x * 32 + dy;
        if (c2 < C && r2 < R) out[(size_t)c2 * R + r2] = tile[threadIdx.x][dy];
    }
}

/* -------- precompute input spike bitmasks: msk[t][q] over all T -------- */
__global__ void __launch_bounds__(256)
inpmask_kernel(const float* __restrict__ in, u64* __restrict__ msk)
{
    const int t    = blockIdx.x * 4 + (threadIdx.x >> 6);
    const int lane = threadIdx.x & 63;
    if (t >= T_STEPS) return;
    const float* __restrict__ row = in + (size_t)t * NI;
    for (int q = 0; q < NIQ; ++q) {
        const int j = q * 64 + lane;
        const u64 m = __ballot(j < NI && row[j] > 0.5f);
        if (lane == 0) msk[t * 16 + q] = m;
    }
}

/* ---------------- persistent SNN kernel ----------------
   mb: [T+1][NBH] slots of 64B. dwords {mask_lo, mask_hi, tag, 0}; slot j
   holds out1(j) with tag j+1. memset-0 per launch (graph replay safety).
   Pipeline: iteration k accumulates gather loads ISSUED at k-1 (= cur(k-1)),
   polls masks o(k-1) published ~2 iterations ago, issues cur(k)'s loads and
   leaves them in flight across a raw lgkmcnt-only barrier; wave0 reduces
   cur(k-1), runs reference step k, publishes o(k+1). */
__global__ void __launch_bounds__(BLOCK)
snn_kernel(const u64*  __restrict__ inpMask,  /* [T][16] */
           const float* __restrict__ W_ro,    /* [NO, NH] row-major */
           const float* __restrict__ Wall,    /* [NROWS, NH] unified W^T */
           float* __restrict__ out,           /* [NO, T] */
           u32*   __restrict__ mb)
{
    const int tid  = threadIdx.x;
    const int lane = tid & 63;
    const int w    = tid >> 6;
    const int b    = blockIdx.x;

    /* ================= readout block (lags freely; full history) ========= */
    if (b == NBH) {
        __shared__ int actR[NH];
        __shared__ int actRn;
        float mem2 = 0.f, syn2 = 0.f;

        for (int t = 0; t < T_STEPS; ++t) {
            if (w == 0) {           /* 64 lanes poll 64 producer slots */
                const u32* tg = &mb[((size_t)t * NBH + lane) * SLOTW];
                v4i r;
                do { r = poll16(tg); } while ((u32)r.z != (u32)(t + 1));
                const u64 m = ((u64)(u32)r.y << 32) | (u32)r.x;
                const int cnt = __popcll(m);
                int v = cnt;
                #pragma unroll
                for (int d = 1; d < 64; d <<= 1) {
                    const int u = __shfl_up(v, d, 64);
                    if (lane >= d) v += u;
                }
                int o = v - cnt;
                if (lane == 63) actRn = v;
                u64 mm = m;
                const int base = lane * 64;
                while (mm) {
                    const int bit = __builtin_ctzll(mm);
                    mm &= mm - 1;
                    actR[o++] = base + bit;
                }
            }
            __syncthreads();

            const int nR = actRn;
            if (tid < NO * 32) {    /* 32 threads per output; 4-way unrolled */
                const int o = tid >> 5, k = tid & 31;
                const float* __restrict__ Wr = W_ro + o * NH;
                float r0 = 0.f, r1 = 0.f, r2 = 0.f, r3 = 0.f;
                int n = k;
                for (; n + 96 < nR; n += 128) {
                    r0 += Wr[actR[n]];      r1 += Wr[actR[n + 32]];
                    r2 += Wr[actR[n + 64]]; r3 += Wr[actR[n + 96]];
                }
                for (; n < nR; n += 32) r0 += Wr[actR[n]];
                float rc = (r0 + r1) + (r2 + r3);
                #pragma unroll
                for (int d = 16; d; d >>= 1) rc += __shfl_xor(rc, d, 32);
                if (k == 0) {
                    const float m2n = mem2 * BETA + syn2;
                    out[o * T_STEPS + t] = m2n;
                    syn2 = syn2 * ALPHA + rc;
                    mem2 = m2n;
                }
            }
            __syncthreads();        /* actR safe to overwrite next iter */
        }
        return;
    }

    /* ================= hidden block ================= */
    __shared__ float pcur[2][BLOCK];           /* partials of cur(k-1)/cur(k) */
    __shared__ int   wl[2][NWAVE][WLCAP];      /* per-wave unified index lists */

    const int i   = b * 64 + lane;             /* this block's weight column */
    const int bb0 = w * SPW;                   /* source blocks owned by wave */
    const int qw  = (w >= NWAVE - NIQ) ? (w - (NWAVE - NIQ)) : -1;
    const float* __restrict__ WallC = Wall + i;

    float M = 0.f, S = 0.f, o_prev = 0.f, o_cur = 0.f;
    float pf[CAP];                             /* in-flight gather window */
    int prevCnt = 0;

    /* publish o_0 = all-zeros (slot 0, tag 1) */
    if (w == 0 && lane == 0) {
        v4i pkt; pkt.x = 0; pkt.y = 0; pkt.z = 1; pkt.w = 0;
        pub16(&mb[(size_t)b * SLOTW], pkt);
    }

    for (int k = 0; k < T_STEPS; ++k) {
        const int pb = (k + 1) & 1;            /* parity of cur(k-1) buffers */

        /* A: accumulate last iteration's prefetched loads = cur(k-1) */
        {
            float s0 = 0.f, s1 = 0.f, s2 = 0.f, s3 = 0.f;
            #pragma unroll
            for (int c = 0; c < NCH; ++c) {
                if (prevCnt > c * 8) {         /* wave-uniform predicate */
                    s0 += pf[c*8+0]; s1 += pf[c*8+1];
                    s2 += pf[c*8+2]; s3 += pf[c*8+3];
                    s0 += pf[c*8+4]; s1 += pf[c*8+5];
                    s2 += pf[c*8+6]; s3 += pf[c*8+7];
                }
            }
            for (int n = CAP; n < prevCnt; ++n)      /* rare overflow path */
                s0 += WallC[(size_t)wl[pb & 1][w][n] * NH];
            pcur[pb][tid] = (s0 + s1) + (s2 + s3);
        }

        /* B: input index extraction for step k (precomputed masks, no comm) */
        int cnt = 0;
        int* mylist = wl[k & 1][w];
        if (qw >= 0) {
            const u64 m = inpMask[(size_t)k * 16 + qw];
            if ((m >> lane) & 1)
                mylist[__popcll(m & (((u64)1 << lane) - 1))] = qw * 64 + lane;
            cnt = __popcll(m);
        }

        /* C+D: poll o(k-1) masks (published ~2 iterations ago) + extract */
        if (k > 0) {
            u64 mk = 0;
            if (lane < SPW) {
                const u32* tg = &mb[((size_t)(k - 1) * NBH + bb0 + lane) * SLOTW];
                v4i r;
                do { r = poll16(tg); } while ((u32)r.z != (u32)k);
                mk = ((u64)(u32)r.y << 32) | (u32)r.x;
            }
            #pragma unroll
            for (int s = 0; s < SPW; ++s) {
                const u64 m = __shfl(mk, s, 64);
                if ((m >> lane) & 1)
                    mylist[cnt + __popcll(m & (((u64)1 << lane) - 1))]
                        = NI + 1 + (bb0 + s) * 64 + lane;
                cnt += __popcll(m);
            }
        }
        /* pad to multiple of 8 with the zero row -> unconditional loads */
        const int padded = (cnt + 7) & ~7;
        if (lane < padded - cnt) mylist[cnt + lane] = ZROW;
        prevCnt = padded;

        /* E: issue cur(k)'s gather loads; leave them in flight */
        #pragma unroll
        for (int c = 0; c < NCH; ++c) {
            if (padded > c * 8) {
                #pragma unroll
                for (int q = 0; q < 8; ++q)
                    pf[c*8+q] = WallC[(size_t)mylist[c*8+q] * NH];
            }
        }

        /* F: raw barrier, LDS-visibility only — NO vmcnt drain */
        asm volatile("s_waitcnt lgkmcnt(0)\n\ts_barrier" ::: "memory");

        /* G: wave0 tail: reduce cur(k-1); reference step k; publish o(k+1) */
        if (w == 0) {
            float cur = 0.f;
            #pragma unroll
            for (int ww = 0; ww < NWAVE; ++ww) cur += pcur[pb][lane + 64 * ww];
            S = S * ALPHA + cur;                 /* S(k) = S(k-1)a + cur(k-1) */
            const float Mr = M * (1.f - o_prev); /* reset with out1(k-1)     */
            M = Mr * BETA + S;                   /* M(k+1) = Mr(k)b + S(k)   */
            const float on = (M * (1.f - o_cur) > 1.f) ? 1.f : 0.f; /* o(k+1) */
            o_prev = o_cur; o_cur = on;
            const u64 sm = __ballot(on > 0.f);
            if (lane == 0) {
                v4i pkt;
                pkt.x = (int)(u32)sm;
                pkt.y = (int)(u32)(sm >> 32);
                pkt.z = (int)(u32)(k + 2);
                pkt.w = 0;
                pub16(&mb[((size_t)(k + 1) * NBH + b) * SLOTW], pkt);
            }
        }
    }
}

extern "C" void kernel_launch(void* const* d_in, const int* in_sizes, int n_in,
                              void* d_out, int out_size, void* d_ws, size_t ws_size,
                              hipStream_t stream)
{
    const float* inp  = (const float*)d_in[0];   /* [T, NI]  */
    const float* W_in = (const float*)d_in[1];   /* [NH, NI] */
    const float* W_fb = (const float*)d_in[2];   /* [NH, NH] */
    const float* W_ro = (const float*)d_in[3];   /* [NO, NH] */
    float* out = (float*)d_out;

    char* ws = (char*)d_ws;
    size_t off = 0;
    auto alloc = [&](size_t bytes) -> void* {
        void* p = ws + off;
        off = (off + bytes + 255) & ~(size_t)255;
        return p;
    };
    /* unified W^T: rows 0..NI-1 = W_in^T, row NI = zeros, NI+1.. = W_fb^T */
    float* Wall    = (float*)alloc(sizeof(float) * (size_t)NROWS * NH);
    u64*   inpMask = (u64*)alloc(sizeof(u64) * (size_t)T_STEPS * 16);
    u32*   mb      = (u32*)alloc(sizeof(u32) * (size_t)(T_STEPS + 1) * NBH * SLOTW);

    /* stale tags from a previous graph replay must be impossible */
    (void)hipMemsetAsync(mb, 0, sizeof(u32) * (size_t)(T_STEPS + 1) * NBH * SLOTW, stream);
    (void)hipMemsetAsync(Wall + (size_t)ZROW * NH, 0, sizeof(float) * NH, stream);

    dim3 tb(32, 8);
    tpose_kernel<<<dim3((NH + 31) / 32, (NH + 31) / 32), tb, 0, stream>>>(
        W_in, Wall, NH, NI);                       /* -> rows 0..NI-1  */
    tpose_kernel<<<dim3((NH + 31) / 32, (NH + 31) / 32), tb, 0, stream>>>(
        W_fb, Wall + (size_t)(NI + 1) * NH, NH, NH); /* -> rows NI+1.. */
    inpmask_kernel<<<(T_STEPS + 3) / 4, 256, 0, stream>>>(inp, inpMask);

    snn_kernel<<<NBH + 1, BLOCK, 0, stream>>>(inpMask, W_ro, Wall, out, mb);
}

// Round 8
// 3674.379 us; speedup vs baseline: 5.8634x; 1.0092x over previous
//
#include <hip/hip_runtime.h>

#define T_STEPS 1000
#define NI 700
#define NIQ 11          /* ceil(NI/64) input mask qwords */
#define NH 4096
#define NO 20

#define ALPHA 0.8187307530779818f   /* exp(-0.2)  synaptic decay */
#define BETA  0.9048374180359595f   /* exp(-0.1)  membrane decay */

#define NBH 64          /* hidden blocks */
#define BLOCK 1024      /* 16 waves */
#define NWAVE 16
#define SLOTW 16        /* u32 per mask slot = 64B line, single writer */
#define NCH 6           /* prefetch chunks of 8 -> 48 register window */
#define CAP (NCH * 8)
#define WLCAP 328       /* 320 max list + pad */
#define NROWS (NI + 1 + NH)

typedef unsigned long long u64;
typedef unsigned int u32;
typedef int v4i __attribute__((ext_vector_type(4)));

/* single-transaction 16B publish / synchronous poll to the coherence point */
__device__ __forceinline__ void pub16(u32* p, v4i v)
{
    asm volatile("global_store_dwordx4 %0, %1, off sc0 sc1"
                 :: "v"((u64)(uintptr_t)p), "v"(v) : "memory");
}
__device__ __forceinline__ v4i poll16(const u32* p)
{
    v4i r;
    asm volatile("global_load_dwordx4 %0, %1, off sc0 sc1\n\ts_waitcnt vmcnt(0)"
                 : "=v"(r) : "v"((u64)(uintptr_t)p) : "memory");
    return r;
}

/* ---------------- transpose: out[c*R + r] = in[r*C + c] ---------------- */
__global__ void __launch_bounds__(256)
tpose_kernel(const float* __restrict__ in, float* __restrict__ out, int R, int C)
{
    __shared__ float tile[32][33];
    const int c  = blockIdx.x * 32 + threadIdx.x;
    const int r0 = blockIdx.y * 32;
    for (int dy = threadIdx.y; dy < 32; dy += 8) {
        const int r = r0 + dy;
        if (r < R && c < C) tile[dy][threadIdx.x] = in[(size_t)r * C + c];
    }
    __syncthreads();
    const int r2 = r0 + threadIdx.x;
    for (int dy = threadIdx.y; dy < 32; dy += 8) {
        const int c2 = blockIdx.x * 32 + dy;
        if (c2 < C && r2 < R) out[(size_t)c2 * R + r2] = tile[threadIdx.x][dy];
    }
}

/* -------- precompute input spike bitmasks: msk[t][q] over all T -------- */
__global__ void __launch_bounds__(256)
inpmask_kernel(const float* __restrict__ in, u64* __restrict__ msk)
{
    const int t    = blockIdx.x * 4 + (threadIdx.x >> 6);
    const int lane = threadIdx.x & 63;
    if (t >= T_STEPS) return;
    const float* __restrict__ row = in + (size_t)t * NI;
    for (int q = 0; q < NIQ; ++q) {
        const int j = q * 64 + lane;
        const u64 m = __ballot(j < NI && row[j] > 0.5f);
        if (lane == 0) msk[t * 16 + q] = m;
    }
}

/* ---------------- persistent SNN kernel ----------------
   mb: [T+1][NBH] 64B slots {mask_lo, mask_hi, tag, 0}; slot j = out1(j),
   tag j+1. Wave 0 of each hidden block = dedicated LIF/publish wave;
   waves 1..15 poll (split-phase), extract, and gather. Gather loads stay
   in flight across a raw lgkmcnt-only barrier and are accumulated next
   iteration. */
__global__ void __launch_bounds__(BLOCK)
snn_kernel(const u64*  __restrict__ inpMask,  /* [T][16] */
           const float* __restrict__ W_ro,    /* [NO, NH] row-major */
           const float* __restrict__ Wall,    /* [NROWS, NH] unified W^T */
           float* __restrict__ out,           /* [NO, T] */
           u32*   __restrict__ mb)
{
    const int tid  = threadIdx.x;
    const int lane = tid & 63;
    const int w    = tid >> 6;
    const int b    = blockIdx.x;

    /* ================= readout block (lags freely; full history) ========= */
    if (b == NBH) {
        __shared__ int actR[NH];
        __shared__ int actRn;
        float mem2 = 0.f, syn2 = 0.f;

        for (int t = 0; t < T_STEPS; ++t) {
            if (w == 0) {           /* 64 lanes poll 64 producer slots */
                const u32* tg = &mb[((size_t)t * NBH + lane) * SLOTW];
                v4i r;
                do { r = poll16(tg); } while ((u32)r.z != (u32)(t + 1));
                const u64 m = ((u64)(u32)r.y << 32) | (u32)r.x;
                const int cnt = __popcll(m);
                int v = cnt;
                #pragma unroll
                for (int d = 1; d < 64; d <<= 1) {
                    const int u = __shfl_up(v, d, 64);
                    if (lane >= d) v += u;
                }
                int o = v - cnt;
                if (lane == 63) actRn = v;
                u64 mm = m;
                const int base = lane * 64;
                while (mm) {
                    const int bit = __builtin_ctzll(mm);
                    mm &= mm - 1;
                    actR[o++] = base + bit;
                }
            }
            __syncthreads();

            const int nR = actRn;
            if (tid < NO * 32) {    /* 32 threads per output; 4-way unrolled */
                const int o = tid >> 5, k = tid & 31;
                const float* __restrict__ Wr = W_ro + o * NH;
                float r0 = 0.f, r1 = 0.f, r2 = 0.f, r3 = 0.f;
                int n = k;
                for (; n + 96 < nR; n += 128) {
                    r0 += Wr[actR[n]];      r1 += Wr[actR[n + 32]];
                    r2 += Wr[actR[n + 64]]; r3 += Wr[actR[n + 96]];
                }
                for (; n < nR; n += 32) r0 += Wr[actR[n]];
                float rc = (r0 + r1) + (r2 + r3);
                #pragma unroll
                for (int d = 16; d; d >>= 1) rc += __shfl_xor(rc, d, 32);
                if (k == 0) {
                    const float m2n = mem2 * BETA + syn2;
                    out[o * T_STEPS + t] = m2n;
                    syn2 = syn2 * ALPHA + rc;
                    mem2 = m2n;
                }
            }
            __syncthreads();        /* actR safe to overwrite next iter */
        }
        return;
    }

    /* ================= hidden block ================= */
    __shared__ float pcur[2][BLOCK];           /* partials of cur(k-1)/cur(k) */
    __shared__ int   wl[2][NWAVE][WLCAP];      /* per-wave float-index lists */

    /* wave roles: w0 = LIF/publish; w1..11: 4 sources + input qword w-1;
       w12..15: 5 sources, no input. */
    const int nsrc = (w == 0) ? 0 : (w <= 11 ? 4 : 5);
    const int srcb = (w <= 11) ? (w - 1) * 4 : 44 + (w - 12) * 5;
    const int qw   = (w >= 1 && w <= 11) ? (w - 1) : -1;
    const int colv = b * 64 + lane;            /* column float-offset */
    const int ZOFF = NI << 12;                 /* zero row float-index base */

    float M = 0.f, S = 0.f, o_prev = 0.f, o_cur = 0.f;
    float pf[CAP];                             /* in-flight gather window */
    int prevCnt = 0;
    v4i rpoll = {0, 0, 0, 0};                  /* split-phase poll packet */

    /* publish o_0 = all-zeros (slot 0, tag 1) */
    if (w == 0 && lane == 0) {
        v4i pkt; pkt.x = 0; pkt.y = 0; pkt.z = 1; pkt.w = 0;
        pub16(&mb[(size_t)b * SLOTW], pkt);
    }

    for (int k = 0; k < T_STEPS; ++k) {
        const int pb = (k + 1) & 1;            /* parity consumed this iter */
        int* mylist = wl[k & 1][w];
        int cnt = 0;

        /* B: input index extraction (no comm dependency) */
        if (qw >= 0) {
            const u64 m = inpMask[(size_t)k * 16 + qw];
            if ((m >> lane) & 1)
                mylist[__popcll(m & (((u64)1 << lane) - 1))]
                    = (qw * 64 + lane) << 12;
            cnt = __popcll(m);
        }

        /* A: accumulate last iteration's prefetched loads = cur(k-1) */
        if (w) {
            float s0 = 0.f, s1 = 0.f, s2 = 0.f, s3 = 0.f;
            #pragma unroll
            for (int c = 0; c < NCH; ++c) {
                if (prevCnt > c * 8) {         /* wave-uniform predicate */
                    s0 += pf[c*8+0]; s1 += pf[c*8+1];
                    s2 += pf[c*8+2]; s3 += pf[c*8+3];
                    s0 += pf[c*8+4]; s1 += pf[c*8+5];
                    s2 += pf[c*8+6]; s3 += pf[c*8+7];
                }
            }
            const int* wlPrev = wl[pb][w];
            for (int n = CAP; n < prevCnt; ++n)      /* rare overflow path */
                s0 += Wall[wlPrev[n] + colv];
            pcur[pb][tid] = (s0 + s1) + (s2 + s3);
        }

        /* CHK+D: check split-phase poll of o(k-1); extract hidden indices */
        if (w && k > 0) {
            u64 mk = 0;
            if (lane < nsrc) {
                /* tie rpoll into the waitcnt so its use can't be hoisted */
                asm volatile("s_waitcnt vmcnt(0)" : "+v"(rpoll) :: "memory");
                if ((u32)rpoll.z != (u32)k) {        /* rare: not yet visible */
                    const u32* tg = &mb[((size_t)(k - 1) * NBH + srcb + lane) * SLOTW];
                    v4i rr;
                    do { rr = poll16(tg); } while ((u32)rr.z != (u32)k);
                    rpoll = rr;
                }
                mk = ((u64)(u32)rpoll.y << 32) | (u32)rpoll.x;
            }
            #pragma unroll
            for (int s = 0; s < 5; ++s) {
                if (s < nsrc) {
                    const u64 m = __shfl(mk, s, 64);
                    if ((m >> lane) & 1)
                        mylist[cnt + __popcll(m & (((u64)1 << lane) - 1))]
                            = (NI + 1 + (srcb + s) * 64 + lane) << 12;
                    cnt += __popcll(m);
                }
            }
        }

        /* pad to multiple of 8 with the zero row -> unconditional loads */
        int padded = 0;
        if (w) {
            padded = (cnt + 7) & ~7;
            if (lane < padded - cnt) mylist[cnt + lane] = ZOFF;
            prevCnt = padded;
        }

        /* E: issue cur(k)'s gather loads; leave them in flight */
        if (w) {
            #pragma unroll
            for (int c = 0; c < NCH; ++c) {
                if (padded > c * 8) {
                    const int4 i0 = *(const int4*)&mylist[c*8];
                    const int4 i1 = *(const int4*)&mylist[c*8+4];
                    pf[c*8+0] = Wall[i0.x + colv];
                    pf[c*8+1] = Wall[i0.y + colv];
                    pf[c*8+2] = Wall[i0.z + colv];
                    pf[c*8+3] = Wall[i0.w + colv];
                    pf[c*8+4] = Wall[i1.x + colv];
                    pf[c*8+5] = Wall[i1.y + colv];
                    pf[c*8+6] = Wall[i1.z + colv];
                    pf[c*8+7] = Wall[i1.w + colv];
                }
            }
        }

        /* P: issue next iteration's mask poll (slot k, tag k+1), no wait */
        if (w && lane < nsrc) {
            const u64 pa = (u64)(uintptr_t)&mb[((size_t)k * NBH + srcb + lane) * SLOTW];
            asm volatile("global_load_dwordx4 %0, %1, off sc0 sc1"
                         : "=v"(rpoll) : "v"(pa) : "memory");
        }

        /* F: raw barrier, LDS-visibility only — NO vmcnt drain */
        asm volatile("s_waitcnt lgkmcnt(0)\n\ts_barrier" ::: "memory");

        /* G: LIF wave: reduce cur(k-1); reference step; publish o(k+1) */
        if (w == 0) {
            float cur = 0.f;
            #pragma unroll
            for (int ww = 1; ww < NWAVE; ++ww) cur += pcur[pb][lane + 64 * ww];
            S = S * ALPHA + cur;                 /* S(k) = S(k-1)a + cur(k-1) */
            const float Mr = M * (1.f - o_prev); /* reset with out1(k-1)     */
            M = Mr * BETA + S;                   /* M(k+1) = Mr(k)b + S(k)   */
            const float on = (M * (1.f - o_cur) > 1.f) ? 1.f : 0.f; /* o(k+1) */
            o_prev = o_cur; o_cur = on;
            const u64 sm = __ballot(on > 0.f);
            if (lane == 0) {
                v4i pkt;
                pkt.x = (int)(u32)sm;
                pkt.y = (int)(u32)(sm >> 32);
                pkt.z = (int)(u32)(k + 2);
                pkt.w = 0;
                pub16(&mb[((size_t)(k + 1) * NBH + b) * SLOTW], pkt);
            }
        }
    }
}

extern "C" void kernel_launch(void* const* d_in, const int* in_sizes, int n_in,
                              void* d_out, int out_size, void* d_ws, size_t ws_size,
                              hipStream_t stream)
{
    const float* inp  = (const float*)d_in[0];   /* [T, NI]  */
    const float* W_in = (const float*)d_in[1];   /* [NH, NI] */
    const float* W_fb = (const float*)d_in[2];   /* [NH, NH] */
    const float* W_ro = (const float*)d_in[3];   /* [NO, NH] */
    float* out = (float*)d_out;

    char* ws = (char*)d_ws;
    size_t off = 0;
    auto alloc = [&](size_t bytes) -> void* {
        void* p = ws + off;
        off = (off + bytes + 255) & ~(size_t)255;
        return p;
    };
    /* unified W^T: rows 0..NI-1 = W_in^T, row NI = zeros, NI+1.. = W_fb^T */
    float* Wall    = (float*)alloc(sizeof(float) * (size_t)NROWS * NH);
    u64*   inpMask = (u64*)alloc(sizeof(u64) * (size_t)T_STEPS * 16);
    u32*   mb      = (u32*)alloc(sizeof(u32) * (size_t)(T_STEPS + 1) * NBH * SLOTW);

    /* stale tags from a previous graph replay must be impossible */
    (void)hipMemsetAsync(mb, 0, sizeof(u32) * (size_t)(T_STEPS + 1) * NBH * SLOTW, stream);
    (void)hipMemsetAsync(Wall + (size_t)NI * NH, 0, sizeof(float) * NH, stream);

    dim3 tb(32, 8);
    tpose_kernel<<<dim3((NH + 31) / 32, (NH + 31) / 32), tb, 0, stream>>>(
        W_in, Wall, NH, NI);                         /* -> rows 0..NI-1  */
    tpose_kernel<<<dim3((NH + 31) / 32, (NH + 31) / 32), tb, 0, stream>>>(
        W_fb, Wall + (size_t)(NI + 1) * NH, NH, NH); /* -> rows NI+1..   */
    inpmask_kernel<<<(T_STEPS + 3) / 4, 256, 0, stream>>>(inp, inpMask);

    snn_kernel<<<NBH + 1, BLOCK, 0, stream>>>(inpMask, W_ro, Wall, out, mb);
}